// Round 7
// baseline (156.246 us; speedup 1.0000x reference)
//
#include <hip/hip_runtime.h>

#define HH 480
#define WW 640
#define NC 3
#define NVX 128           // W/SKIP
#define NVY 96            // H/SKIP
#define NV (NVX * NVY)    // 12288
#define NBX 80
#define NBY 60
#define NB (NBX * NBY)    // 4800
#define NPB 96                       // point buckets (96*128 == NV)
#define BKT 128                      // bucket capacity
#define NLANE 1200                   // (NBX/2)*(NBY/2) 2x2 bin tiles
#define XBLK 5                       // ceil(NLANE/256)

// ---------------- kernel 1: gather + per-bucket stable compaction (vl>0 only) ----------------
__global__ void precompute_pts(const int* __restrict__ label,
                               const float* __restrict__ vert,
                               float4* __restrict__ ptsA,
                               float4* __restrict__ ptsB,
                               int* __restrict__ cnt,
                               float* __restrict__ blockCounts) {
    __shared__ int swtot[2], sn2[2];
    const int tid = threadIdx.x;                 // 0..127
    const int i = blockIdx.x * BKT + tid;        // < NV (96*128 == 12288)
    const int iy = i >> 7;
    const int ix = i & (NVX - 1);
    const int pix = (5 * iy) * WW + 5 * ix;
    const int vl = label[pix];
    const float* base = vert + (size_t)(vl * 3) * HH * WW + pix;
    const float ux = base[0];
    const float uy = base[(size_t)HH * WW];
    const float dist = base[(size_t)2 * HH * WW];

    const bool pos = (vl > 0);
    const int lane = tid & 63, w = tid >> 6;
    unsigned long long mp = __ballot(pos);
    unsigned long long m2 = __ballot(vl == 2);
    int rank = __popcll(mp & ((1ull << lane) - 1ull));
    if (lane == 0) { swtot[w] = __popcll(mp); sn2[w] = __popcll(m2); }
    __syncthreads();
    if (pos) {
        int p = blockIdx.x * BKT + (w ? swtot[0] : 0) + rank;
        ptsA[p] = make_float4((float)(5 * ix), (float)(5 * iy), ux, uy);
        ptsB[p] = make_float4((vl == 1) ? dist : 0.0f,
                              (vl == 2) ? dist : 0.0f,
                              (vl == 1) ? 1.0f : 0.0f,
                              (vl == 2) ? 1.0f : 0.0f);
    }
    if (tid == 0) {
        int tot = swtot[0] + swtot[1];
        int n2 = sn2[0] + sn2[1];
        cnt[blockIdx.x] = tot;
        blockCounts[blockIdx.x * NC + 0] = (float)(BKT - tot);
        blockCounts[blockIdx.x * NC + 1] = (float)(tot - n2);
        blockCounts[blockIdx.x * NC + 2] = (float)n2;
    }
}

// ---------------- kernel 2: voting, 2x2 bins/lane, NO atomics ----------------
// Fast test: cos>0.5 <=> dot>0 && s>0, s = dot^2 - 0.25*nx. Flag band
// |s| < nx*4e-6 (>=10x the fast-vs-exact disagreement zone ~3.6e-7): flagged
// lanes re-run the bucket post-loop applying (m_exact - m_fast) deltas with
// the reference's exact IEEE sequence. All reproducible ops use explicit
// _rn/fma intrinsics so both passes compile to identical instruction
// sequences (no fp-contract divergence). Partial sums stored plain ->
// partial[y][plane][NB], plane in {h1,h2,d1,d2}.
__global__ void vote(const float4* __restrict__ ptsA,
                     const float4* __restrict__ ptsB,
                     const int* __restrict__ cnt,
                     float* __restrict__ partial) {
    __shared__ float4 shA[BKT];
    __shared__ float4 shB[BKT];
    const int tid = threadIdx.x;
    const int p0 = blockIdx.y * BKT;
    if (tid < BKT) shA[tid] = ptsA[p0 + tid];
    else           shB[tid - BKT] = ptsB[p0 + tid - BKT];
    const int n = cnt[blockIdx.y];

    const int gi = blockIdx.x * 256 + tid;       // < 1280, active < 1200
    const int xp = gi % 40;
    const int yp = gi / 40;                      // 0..31 (valid <30)
    const float bx0 = (float)(4 + 16 * xp), bx1 = bx0 + 8.0f;
    const float by0 = (float)(4 + 16 * yp), by1 = by0 + 8.0f;

    float hh1[4] = {0.f, 0.f, 0.f, 0.f};
    float hh2[4] = {0.f, 0.f, 0.f, 0.f};
    float dd1[4] = {0.f, 0.f, 0.f, 0.f};
    float dd2[4] = {0.f, 0.f, 0.f, 0.f};
    float flagacc = -1.0f;
    __syncthreads();

#pragma unroll 2
    for (int j = 0; j < n; ++j) {
        float4 a = shA[j];   // vx, vy, ux, uy
        float4 q = shB[j];   // z1, z2, c1, c2
        float ddx[2] = {__fsub_rn(bx0, a.x), __fsub_rn(bx1, a.x)};
        float ddy[2] = {__fsub_rn(by0, a.y), __fsub_rn(by1, a.y)};
        float dxu[2], dyt[2], dyu[2];
#pragma unroll
        for (int c = 0; c < 2; ++c) dxu[c] = __fmul_rn(ddx[c], a.z);
#pragma unroll
        for (int r = 0; r < 2; ++r) {
            dyt[r] = __builtin_fmaf(ddy[r], ddy[r], 1e-6f);
            dyu[r] = __fmul_rn(ddy[r], a.w);
        }
#pragma unroll
        for (int bb = 0; bb < 4; ++bb) {
            const int r = bb >> 1, c = bb & 1;
            float nx = __builtin_fmaf(ddx[c], ddx[c], dyt[r]);
            float dt = __fadd_rn(dxu[c], dyu[r]);
            float s  = __builtin_fmaf(dt, dt, __fmul_rn(-0.25f, nx));
            float g  = fminf(dt, s);
            float f  = fminf(dt, __builtin_fmaf(nx, 4e-6f, -fabsf(s)));
            flagacc  = fmaxf(flagacc, f);
            float m  = (g > 0.0f) ? 1.0f : 0.0f;
            hh1[bb] = __builtin_fmaf(m, q.z, hh1[bb]);
            hh2[bb] = __builtin_fmaf(m, q.w, hh2[bb]);
            dd1[bb] = __builtin_fmaf(m, q.x, dd1[bb]);
            dd2[bb] = __builtin_fmaf(m, q.y, dd2[bb]);
        }
    }

    // ---- rare correction pass (flagged lanes only) ----
    if (gi >= NLANE) flagacc = -1.0f;
    if (flagacc > 0.0f) {
        for (int j = 0; j < n; ++j) {
            float4 a = shA[j];
            float4 q = shB[j];
            float ddx[2] = {__fsub_rn(bx0, a.x), __fsub_rn(bx1, a.x)};
            float ddy[2] = {__fsub_rn(by0, a.y), __fsub_rn(by1, a.y)};
            float dxu[2], dyt[2], dyu[2];
#pragma unroll
            for (int c = 0; c < 2; ++c) dxu[c] = __fmul_rn(ddx[c], a.z);
#pragma unroll
            for (int r = 0; r < 2; ++r) {
                dyt[r] = __builtin_fmaf(ddy[r], ddy[r], 1e-6f);
                dyu[r] = __fmul_rn(ddy[r], a.w);
            }
#pragma unroll
            for (int bb = 0; bb < 4; ++bb) {
                const int r = bb >> 1, c = bb & 1;
                // identical fast sequence
                float nx = __builtin_fmaf(ddx[c], ddx[c], dyt[r]);
                float dt = __fadd_rn(dxu[c], dyu[r]);
                float s  = __builtin_fmaf(dt, dt, __fmul_rn(-0.25f, nx));
                float mf = (fminf(dt, s) > 0.0f) ? 1.0f : 0.0f;
                // exact reference sequence
                float nxe  = __fadd_rn(__fadd_rn(__fmul_rn(ddx[c], ddx[c]),
                                                 __fmul_rn(ddy[r], ddy[r])), 1e-6f);
                float inve = __fdiv_rn(1.0f, __fsqrt_rn(nxe));
                float dote = __fadd_rn(__fmul_rn(ddx[c], a.z),
                                       __fmul_rn(ddy[r], a.w));
                float me   = (__fmul_rn(dote, inve) > 0.5f) ? 1.0f : 0.0f;
                float dm   = me - mf;   // in {-1,0,1}, exact
                hh1[bb] = __builtin_fmaf(dm, q.z, hh1[bb]);
                hh2[bb] = __builtin_fmaf(dm, q.w, hh2[bb]);
                dd1[bb] = __builtin_fmaf(dm, q.x, dd1[bb]);
                dd2[bb] = __builtin_fmaf(dm, q.y, dd2[bb]);
            }
        }
    }

    if (gi < NLANE) {
        const int r0 = 2 * yp, c0 = 2 * xp;
        float* base = partial + (size_t)blockIdx.y * 4 * NB;
        *(float2*)&base[0 * NB + r0 * NBX + c0]       = make_float2(hh1[0], hh1[1]);
        *(float2*)&base[0 * NB + (r0 + 1) * NBX + c0] = make_float2(hh1[2], hh1[3]);
        *(float2*)&base[1 * NB + r0 * NBX + c0]       = make_float2(hh2[0], hh2[1]);
        *(float2*)&base[1 * NB + (r0 + 1) * NBX + c0] = make_float2(hh2[2], hh2[3]);
        *(float2*)&base[2 * NB + r0 * NBX + c0]       = make_float2(dd1[0], dd1[1]);
        *(float2*)&base[2 * NB + (r0 + 1) * NBX + c0] = make_float2(dd1[2], dd1[3]);
        *(float2*)&base[3 * NB + r0 * NBX + c0]       = make_float2(dd2[0], dd2[1]);
        *(float2*)&base[3 * NB + (r0 + 1) * NBX + c0] = make_float2(dd2[2], dd2[3]);
    }
}

// ---------------- kernel 2b: tree-reduce partials (deterministic y order) ----------------
__global__ void reduce(const float* __restrict__ partial,
                       float* __restrict__ hough,
                       float* __restrict__ dsum) {
    const int t = blockIdx.x * 256 + threadIdx.x;   // < 4*NB = 19200
    const int plane = t / NB;
    const int b = t % NB;
    const float* p = partial + plane * NB + b;
    float s = 0.0f;
#pragma unroll 8
    for (int y = 0; y < NPB; ++y) s += p[(size_t)y * 4 * NB];
    if (plane == 0) { hough[b] = 0.0f; hough[NB + b] = s; }
    else if (plane == 1) hough[2 * NB + b] = s;
    else if (plane == 2) dsum[b] = s;
    else                 dsum[NB + b] = s;
}

// ---------------- kernel 3: argmax + ROI math (one block per class) ----------------
__global__ void finalize(const float* __restrict__ hough,
                         const float* __restrict__ dsum,
                         const float* __restrict__ blockCounts,
                         const float* __restrict__ meta,
                         const float* __restrict__ extents,
                         float* __restrict__ rois) {
    __shared__ unsigned long long skey[256];
    __shared__ float scnt[256];
    const int tid = threadIdx.x;
    const int c = blockIdx.x;

    float cntv = 0.0f;
    for (int i = tid; i < NPB; i += 256) cntv += blockCounts[i * NC + c];
    scnt[tid] = cntv;

    unsigned long long best = 0ull;
    for (int i = tid; i < NB; i += 256) {
        float v = hough[c * NB + i];
        unsigned long long key =
            ((unsigned long long)__float_as_uint(v) << 32) |
            (unsigned long long)(unsigned)(NB - 1 - i);
        if (key > best) best = key;
    }
    skey[tid] = best;
    __syncthreads();
    for (int s = 128; s > 0; s >>= 1) {
        if (tid < s) {
            if (skey[tid + s] > skey[tid]) skey[tid] = skey[tid + s];
            scnt[tid] += scnt[tid + s];
        }
        __syncthreads();
    }
    if (tid == 0) {
        float votes = __uint_as_float((unsigned)(skey[0] >> 32));
        int peak = NB - 1 - (int)(skey[0] & 0xffffffffull);
        float ds = (c == 0) ? 0.0f : dsum[(c - 1) * NB + peak];
        float depth = __fdiv_rn(ds, fmaxf(votes, 1.0f));
        float cx = (float)(4 + 8 * (peak % NBX));
        float cy = (float)(4 + 8 * (peak / NBX));
        float cntf = scnt[0];
        float score = __fdiv_rn(votes, fmaxf(cntf, 1.0f));
        int valid = (cntf > 5.0f) && (score > 0.3f);
        float fx = meta[0], fy = meta[4];
        float e0 = extents[c * 3 + 0];
        float e1 = extents[c * 3 + 1];
        float e2 = extents[c * 3 + 2];
        float diag = __fsqrt_rn(__fadd_rn(
            __fadd_rn(__fmul_rn(e0, e0), __fmul_rn(e1, e1)), __fmul_rn(e2, e2)));
        float sz = fmaxf(fabsf(depth), 0.001f);
        float bw = __fdiv_rn(fabsf(__fmul_rn(diag, fx)), sz);
        float bh = __fdiv_rn(fabsf(__fmul_rn(diag, fy)), sz);
        rois[c * 6 + 0] = (float)c;
        rois[c * 6 + 1] = cx - bw * 0.5f;
        rois[c * 6 + 2] = cy - bh * 0.5f;
        rois[c * 6 + 3] = cx + bw * 0.5f;
        rois[c * 6 + 4] = cy + bh * 0.5f;
        rois[c * 6 + 5] = valid ? score : 0.0f;
    }
}

extern "C" void kernel_launch(void* const* d_in, const int* in_sizes, int n_in,
                              void* d_out, int out_size, void* d_ws, size_t ws_size,
                              hipStream_t stream) {
    const int* label = (const int*)d_in[0];
    const float* vert = (const float*)d_in[1];
    const float* meta = (const float*)d_in[2];
    const float* extents = (const float*)d_in[3];
    float* out = (float*)d_out;

    char* ws = (char*)d_ws;
    size_t off = 0;
    float4* ptsA = (float4*)(ws + off); off += (size_t)NV * 16;        // 196608
    float4* ptsB = (float4*)(ws + off); off += (size_t)NV * 16;        // 196608
    float* partial = (float*)(ws + off); off += (size_t)NPB * 4 * NB * 4; // 7372800
    float* dsum = (float*)(ws + off); off += (size_t)2 * NB * 4;       // 38400
    float* blockCounts = (float*)(ws + off); off += (size_t)NPB * NC * 4; // 1152
    int* cnt = (int*)(ws + off);                                        // 384

    float* hough = out + NC * 6;  // 3*NB floats; rois occupy out[0..17]

    precompute_pts<<<NPB, BKT, 0, stream>>>(label, vert, ptsA, ptsB,
                                            cnt, blockCounts);
    vote<<<dim3(XBLK, NPB), 256, 0, stream>>>(ptsA, ptsB, cnt, partial);
    reduce<<<(4 * NB) / 256, 256, 0, stream>>>(partial, hough, dsum);
    finalize<<<NC, 256, 0, stream>>>(hough, dsum, blockCounts, meta, extents, out);
}

// Round 8
// 106.139 us; speedup vs baseline: 1.4721x; 1.4721x over previous
//
#include <hip/hip_runtime.h>

#define HH 480
#define WW 640
#define NC 3
#define NVX 128           // W/SKIP
#define NVY 96            // H/SKIP
#define NV (NVX * NVY)    // 12288
#define NBX 80
#define NBY 60
#define NB (NBX * NBY)    // 4800
#define NBKT 192                     // point buckets (192*64 == NV), 1 wave each
#define BKT 64                       // bucket capacity
#define PCB (NBKT / 4)               // precompute blocks (256 thr = 4 buckets)
#define XBLK 10                      // 2560 lanes >= 2400 = NB/2
#define RBLK 300                     // reduce blocks (76800 thr = 4*19200)

// ---------------- kernel 1: gather + per-wave class-sorted compaction ----------------
// Bucket = one wave of 64 sample indices. Layout per bucket: class-1 points
// (ascending original order) then class-2 (ascending). ptsA=(vx,vy,2ux,2uy),
// ptsZ=dist. cnts[bucket]=(n1, n1+n2) packed as 2x int16 in one int.
__global__ void precompute_pts(const int* __restrict__ label,
                               const float* __restrict__ vert,
                               float4* __restrict__ ptsA,
                               float* __restrict__ ptsZ,
                               int* __restrict__ cnts,
                               float* __restrict__ blockCounts) {
    const int tid = threadIdx.x;
    const int i = blockIdx.x * 256 + tid;        // < NV
    const int lane = tid & 63;
    const int bucket = i >> 6;
    const int iy = i >> 7;
    const int ix = i & (NVX - 1);
    const int pix = (5 * iy) * WW + 5 * ix;
    const int vl = label[pix];
    const float* base = vert + (size_t)(vl * 3) * HH * WW + pix;
    const float ux = base[0];
    const float uy = base[(size_t)HH * WW];
    const float dist = base[(size_t)2 * HH * WW];

    unsigned long long m1 = __ballot(vl == 1);
    unsigned long long m2 = __ballot(vl == 2);
    const int n1 = __popcll(m1);
    const int n2 = __popcll(m2);
    const unsigned long long below = (1ull << lane) - 1ull;
    int pos = -1;
    if (vl == 1) pos = bucket * BKT + __popcll(m1 & below);
    else if (vl == 2) pos = bucket * BKT + n1 + __popcll(m2 & below);
    if (pos >= 0) {
        ptsA[pos] = make_float4((float)(5 * ix), (float)(5 * iy),
                                __fmul_rn(2.0f, ux), __fmul_rn(2.0f, uy));
        ptsZ[pos] = dist;
    }
    if (lane == 0) {
        cnts[bucket] = n1 | ((n1 + n2) << 16);
        blockCounts[bucket * NC + 0] = (float)(BKT - n1 - n2);
        blockCounts[bucket * NC + 1] = (float)n1;
        blockCounts[bucket * NC + 2] = (float)n2;
    }
}

// ---------------- kernel 2: voting, 2 bins/lane, class-segmented, no atomics ----------------
// Fast test (u pre-scaled by 2): cos>0.5 <=> dot2>0 && s>0, s=dot2^2-nx.
// Disagreement with the exact reference sequence only possible when
// |s| < nx*4e-6 (>=4x combined rounding band); flagged lanes re-run the
// bucket post-loop applying (m_exact - m_fast) deltas in {-1,0,1} ->
// hough counts exact ints, all decisions bit-identical to np reference.
__global__ void vote(const float4* __restrict__ ptsA,
                     const float* __restrict__ ptsZ,
                     const int* __restrict__ cnts,
                     float* __restrict__ partial) {
    __shared__ float4 shA[BKT];
    __shared__ float shZ[BKT];
    const int tid = threadIdx.x;
    const int p0 = blockIdx.y * BKT;
    if (tid < BKT) { shA[tid] = ptsA[p0 + tid]; shZ[tid] = ptsZ[p0 + tid]; }
    const int packed = cnts[blockIdx.y];
    const int n1 = packed & 0xffff;
    const int nt = packed >> 16;

    const int gi = blockIdx.x * 256 + tid;       // < 2560, active < 2400
    const int b0 = 2 * gi;
    const float bx0 = (float)(4 + 8 * (b0 % NBX));
    const float bx1 = bx0 + 8.0f;
    const float byf = (float)(4 + 8 * (b0 / NBX));
    float h1a = 0.f, h1b = 0.f, d1a = 0.f, d1b = 0.f;
    float h2a = 0.f, h2b = 0.f, d2a = 0.f, d2b = 0.f;
    float flagacc = -1.0f;
    __syncthreads();

#pragma unroll 2
    for (int j = 0; j < n1; ++j) {               // class-1 segment
        float4 a = shA[j];
        float z = shZ[j];
        float ddy = __fsub_rn(byf, a.y);
        float dyt = __builtin_fmaf(ddy, ddy, 1e-6f);
        float dyu = __fmul_rn(ddy, a.w);
        float ddx0 = __fsub_rn(bx0, a.x);
        float ddx1 = __fsub_rn(bx1, a.x);
        float nx0 = __builtin_fmaf(ddx0, ddx0, dyt);
        float nx1 = __builtin_fmaf(ddx1, ddx1, dyt);
        float dt0 = __builtin_fmaf(ddx0, a.z, dyu);
        float dt1 = __builtin_fmaf(ddx1, a.z, dyu);
        float s0 = __builtin_fmaf(dt0, dt0, -nx0);
        float s1 = __builtin_fmaf(dt1, dt1, -nx1);
        flagacc = fmaxf(flagacc, __builtin_fmaf(nx0, 4e-6f, -fabsf(s0)));
        flagacc = fmaxf(flagacc, __builtin_fmaf(nx1, 4e-6f, -fabsf(s1)));
        float m0 = (fminf(dt0, s0) > 0.0f) ? 1.0f : 0.0f;
        float m1_ = (fminf(dt1, s1) > 0.0f) ? 1.0f : 0.0f;
        h1a += m0; d1a = __builtin_fmaf(m0, z, d1a);
        h1b += m1_; d1b = __builtin_fmaf(m1_, z, d1b);
    }
#pragma unroll 2
    for (int j = n1; j < nt; ++j) {              // class-2 segment
        float4 a = shA[j];
        float z = shZ[j];
        float ddy = __fsub_rn(byf, a.y);
        float dyt = __builtin_fmaf(ddy, ddy, 1e-6f);
        float dyu = __fmul_rn(ddy, a.w);
        float ddx0 = __fsub_rn(bx0, a.x);
        float ddx1 = __fsub_rn(bx1, a.x);
        float nx0 = __builtin_fmaf(ddx0, ddx0, dyt);
        float nx1 = __builtin_fmaf(ddx1, ddx1, dyt);
        float dt0 = __builtin_fmaf(ddx0, a.z, dyu);
        float dt1 = __builtin_fmaf(ddx1, a.z, dyu);
        float s0 = __builtin_fmaf(dt0, dt0, -nx0);
        float s1 = __builtin_fmaf(dt1, dt1, -nx1);
        flagacc = fmaxf(flagacc, __builtin_fmaf(nx0, 4e-6f, -fabsf(s0)));
        flagacc = fmaxf(flagacc, __builtin_fmaf(nx1, 4e-6f, -fabsf(s1)));
        float m0 = (fminf(dt0, s0) > 0.0f) ? 1.0f : 0.0f;
        float m1_ = (fminf(dt1, s1) > 0.0f) ? 1.0f : 0.0f;
        h2a += m0; d2a = __builtin_fmaf(m0, z, d2a);
        h2b += m1_; d2b = __builtin_fmaf(m1_, z, d2b);
    }

    // ---- rare correction pass (flagged lanes only) ----
    if (gi >= NB / 2) flagacc = -1.0f;
    if (flagacc > 0.0f) {
        for (int j = 0; j < nt; ++j) {
            float4 a = shA[j];
            float z = shZ[j];
            float ddy = __fsub_rn(byf, a.y);
            float dyt = __builtin_fmaf(ddy, ddy, 1e-6f);
            float dyu = __fmul_rn(ddy, a.w);
#pragma unroll
            for (int k = 0; k < 2; ++k) {
                float bx = k ? bx1 : bx0;
                float ddx = __fsub_rn(bx, a.x);
                // identical fast sequence
                float nx = __builtin_fmaf(ddx, ddx, dyt);
                float dt = __builtin_fmaf(ddx, a.z, dyu);
                float s  = __builtin_fmaf(dt, dt, -nx);
                float mf = (fminf(dt, s) > 0.0f) ? 1.0f : 0.0f;
                // exact reference sequence (undo the 2x on u via 0.5*)
                float uxe = __fmul_rn(0.5f, a.z), uye = __fmul_rn(0.5f, a.w);
                float nxe  = __fadd_rn(__fadd_rn(__fmul_rn(ddx, ddx),
                                                 __fmul_rn(ddy, ddy)), 1e-6f);
                float inve = __fdiv_rn(1.0f, __fsqrt_rn(nxe));
                float dote = __fadd_rn(__fmul_rn(ddx, uxe), __fmul_rn(ddy, uye));
                float me   = (__fmul_rn(dote, inve) > 0.5f) ? 1.0f : 0.0f;
                float dm   = me - mf;   // in {-1,0,1}, exact
                if (j < n1) {
                    if (k == 0) { h1a += dm; d1a = __builtin_fmaf(dm, z, d1a); }
                    else        { h1b += dm; d1b = __builtin_fmaf(dm, z, d1b); }
                } else {
                    if (k == 0) { h2a += dm; d2a = __builtin_fmaf(dm, z, d2a); }
                    else        { h2b += dm; d2b = __builtin_fmaf(dm, z, d2b); }
                }
            }
        }
    }

    if (gi < NB / 2) {
        float* base = partial + (size_t)blockIdx.y * 4 * NB;
        *(float2*)&base[0 * NB + b0] = make_float2(h1a, h1b);
        *(float2*)&base[1 * NB + b0] = make_float2(h2a, h2b);
        *(float2*)&base[2 * NB + b0] = make_float2(d1a, d1b);
        *(float2*)&base[3 * NB + b0] = make_float2(d2a, d2b);
    }
}

// ---------------- kernel 2b: reduce partials over 192 buckets ----------------
// 4 threads per (plane,bin); each sums 48 consecutive y's sequentially, then
// ordered low->high combine in LDS. Hough sums are exact integers.
__global__ void reduce(const float* __restrict__ partial,
                       float* __restrict__ hough,
                       float* __restrict__ dsum) {
    __shared__ float acc[4][64];
    const int tid = threadIdx.x;
    const int sub = tid >> 6;                    // 0..3
    const int idx = blockIdx.x * 64 + (tid & 63);  // < 19200, one plane per block
    const float* p = partial + idx;
    float s = 0.0f;
#pragma unroll 8
    for (int y = sub * 48; y < sub * 48 + 48; ++y) s += p[(size_t)y * 4 * NB];
    acc[sub][tid & 63] = s;
    __syncthreads();
    if (sub == 0) {
        const int l = tid & 63;
        float t = ((acc[0][l] + acc[1][l]) + acc[2][l]) + acc[3][l];
        const int plane = idx / NB;
        const int b = idx % NB;
        if (plane == 0) { hough[b] = 0.0f; hough[NB + b] = t; }
        else if (plane == 1) hough[2 * NB + b] = t;
        else if (plane == 2) dsum[b] = t;
        else                 dsum[NB + b] = t;
    }
}

// ---------------- kernel 3: argmax + ROI math (one block per class) ----------------
__global__ void finalize(const float* __restrict__ hough,
                         const float* __restrict__ dsum,
                         const float* __restrict__ blockCounts,
                         const float* __restrict__ meta,
                         const float* __restrict__ extents,
                         float* __restrict__ rois) {
    __shared__ unsigned long long skey[256];
    __shared__ float scnt[256];
    const int tid = threadIdx.x;
    const int c = blockIdx.x;

    float cntv = 0.0f;
    for (int i = tid; i < NBKT; i += 256) cntv += blockCounts[i * NC + c];
    scnt[tid] = cntv;

    unsigned long long best = 0ull;
    for (int i = tid; i < NB; i += 256) {
        float v = hough[c * NB + i];
        unsigned long long key =
            ((unsigned long long)__float_as_uint(v) << 32) |
            (unsigned long long)(unsigned)(NB - 1 - i);
        if (key > best) best = key;
    }
    skey[tid] = best;
    __syncthreads();
    for (int s = 128; s > 0; s >>= 1) {
        if (tid < s) {
            if (skey[tid + s] > skey[tid]) skey[tid] = skey[tid + s];
            scnt[tid] += scnt[tid + s];
        }
        __syncthreads();
    }
    if (tid == 0) {
        float votes = __uint_as_float((unsigned)(skey[0] >> 32));
        int peak = NB - 1 - (int)(skey[0] & 0xffffffffull);
        float ds = (c == 0) ? 0.0f : dsum[(c - 1) * NB + peak];
        float depth = __fdiv_rn(ds, fmaxf(votes, 1.0f));
        float cx = (float)(4 + 8 * (peak % NBX));
        float cy = (float)(4 + 8 * (peak / NBX));
        float cntf = scnt[0];
        float score = __fdiv_rn(votes, fmaxf(cntf, 1.0f));
        int valid = (cntf > 5.0f) && (score > 0.3f);
        float fx = meta[0], fy = meta[4];
        float e0 = extents[c * 3 + 0];
        float e1 = extents[c * 3 + 1];
        float e2 = extents[c * 3 + 2];
        float diag = __fsqrt_rn(__fadd_rn(
            __fadd_rn(__fmul_rn(e0, e0), __fmul_rn(e1, e1)), __fmul_rn(e2, e2)));
        float sz = fmaxf(fabsf(depth), 0.001f);
        float bw = __fdiv_rn(fabsf(__fmul_rn(diag, fx)), sz);
        float bh = __fdiv_rn(fabsf(__fmul_rn(diag, fy)), sz);
        rois[c * 6 + 0] = (float)c;
        rois[c * 6 + 1] = cx - bw * 0.5f;
        rois[c * 6 + 2] = cy - bh * 0.5f;
        rois[c * 6 + 3] = cx + bw * 0.5f;
        rois[c * 6 + 4] = cy + bh * 0.5f;
        rois[c * 6 + 5] = valid ? score : 0.0f;
    }
}

extern "C" void kernel_launch(void* const* d_in, const int* in_sizes, int n_in,
                              void* d_out, int out_size, void* d_ws, size_t ws_size,
                              hipStream_t stream) {
    const int* label = (const int*)d_in[0];
    const float* vert = (const float*)d_in[1];
    const float* meta = (const float*)d_in[2];
    const float* extents = (const float*)d_in[3];
    float* out = (float*)d_out;

    char* ws = (char*)d_ws;
    size_t off = 0;
    float4* ptsA = (float4*)(ws + off); off += (size_t)NV * 16;           // 196608
    float* ptsZ = (float*)(ws + off); off += (size_t)NV * 4;              // 49152
    float* partial = (float*)(ws + off); off += (size_t)NBKT * 4 * NB * 4; // 14745600
    float* dsum = (float*)(ws + off); off += (size_t)2 * NB * 4;          // 38400
    float* blockCounts = (float*)(ws + off); off += (size_t)NBKT * NC * 4; // 2304
    int* cnts = (int*)(ws + off);                                          // 768

    float* hough = out + NC * 6;  // 3*NB floats; rois occupy out[0..17]

    precompute_pts<<<PCB, 256, 0, stream>>>(label, vert, ptsA, ptsZ,
                                            cnts, blockCounts);
    vote<<<dim3(XBLK, NBKT), 256, 0, stream>>>(ptsA, ptsZ, cnts, partial);
    reduce<<<RBLK, 256, 0, stream>>>(partial, hough, dsum);
    finalize<<<NC, 256, 0, stream>>>(hough, dsum, blockCounts, meta, extents, out);
}